// Round 8
// baseline (489.927 us; speedup 1.0000x reference)
//
#include <hip/hip_runtime.h>

#define NN 20000
#define NE 640000
#define NR 8
#define NSEG (NN * NR)
#define KCAT 2304            // logical K: 256 self + 8*256 relations
#define KA   2048            // A stores only the 8 relation blocks
#define CH1 256
#define CH2 128

typedef __attribute__((ext_vector_type(8))) short short8;
typedef __attribute__((ext_vector_type(4))) float f32x4;

#define AS_GLOBAL __attribute__((address_space(1)))
#define AS_LDS    __attribute__((address_space(3)))

__device__ __forceinline__ float bf2f(unsigned short u) {
    unsigned int x = ((unsigned int)u) << 16;
    return __builtin_bit_cast(float, x);
}
__device__ __forceinline__ unsigned short f2bf(float f) {
    unsigned int u = __builtin_bit_cast(unsigned int, f);
    u = (u + 0x7FFFu + ((u >> 16) & 1u)) >> 16;   // RNE
    return (unsigned short)u;
}
__device__ __forceinline__ f32x4 cvt4(ushort4 v) {
    f32x4 r;
    r.x = bf2f(v.x); r.y = bf2f(v.y); r.z = bf2f(v.z); r.w = bf2f(v.w);
    return r;
}
__device__ __forceinline__ ushort4 ldrow(const unsigned short* xb, int s, int lane) {
    return reinterpret_cast<const ushort4*>(xb + (size_t)s * 256)[lane];
}

// ================= fused prologue: edge count + x->bf16 =================
__global__ void prologue1(const int* __restrict__ dst, const int* __restrict__ et,
                          int* __restrict__ cnt,
                          const float* __restrict__ x, unsigned short* __restrict__ xbf) {
    int gid = blockIdx.x * 256 + threadIdx.x;
    if (gid < NN * 64) {
        float4 v = reinterpret_cast<const float4*>(x)[gid];
        ushort4 o;
        o.x = f2bf(v.x); o.y = f2bf(v.y); o.z = f2bf(v.z); o.w = f2bf(v.w);
        reinterpret_cast<ushort4*>(xbf)[gid] = o;
    }
    if (gid < NE) atomicAdd(&cnt[et[gid] * NN + dst[gid]], 1);
}

// ================= scans =================
__global__ void scan1(const int* __restrict__ cnt, int* __restrict__ off,
                      int* __restrict__ bsum) {
    __shared__ int s[256];
    int i = blockIdx.x * 256 + threadIdx.x;
    int v = (i < NSEG) ? cnt[i] : 0;
    s[threadIdx.x] = v;
    __syncthreads();
    for (int d = 1; d < 256; d <<= 1) {
        int t = (threadIdx.x >= d) ? s[threadIdx.x - d] : 0;
        __syncthreads();
        s[threadIdx.x] += t;
        __syncthreads();
    }
    if (i < NSEG) off[i] = s[threadIdx.x] - v;
    if (threadIdx.x == 255) bsum[blockIdx.x] = s[255];
}

__global__ __launch_bounds__(1024) void scan2(int* __restrict__ bsum, int nb) {
    __shared__ int s[1024];
    int t = threadIdx.x;
    int v = (t < nb) ? bsum[t] : 0;
    s[t] = v;
    __syncthreads();
    for (int d = 1; d < 1024; d <<= 1) {
        int tv = (t >= d) ? s[t - d] : 0;
        __syncthreads();
        s[t] += tv;
        __syncthreads();
    }
    if (t < nb) bsum[t] = s[t] - v;   // exclusive
}

__global__ void scan3(int* __restrict__ off, const int* __restrict__ bsum,
                      int* __restrict__ cursor) {
    int i = blockIdx.x * 256 + threadIdx.x;
    if (i < NSEG) {
        int o = off[i] + bsum[blockIdx.x];
        off[i] = o;
        cursor[i] = o;
    }
}

__global__ void bucket_kernel(const int* __restrict__ src, const int* __restrict__ dst,
                              const int* __restrict__ et, int* __restrict__ cursor,
                              int* __restrict__ ss) {
    int e = blockIdx.x * blockDim.x + threadIdx.x;
    if (e < NE) {
        int p = atomicAdd(&cursor[et[e] * NN + dst[e]], 1);
        ss[p] = src[e];
    }
}

// ================= both weight transposes in one kernel =================
// WT[n][k]: k<256 -> root[k][n]; else W flat (k-256)*nout + n   (W is [R*256][nout])
__global__ void build_wt_all(const float* __restrict__ root1, const float* __restrict__ W1,
                             const float* __restrict__ root2, const float* __restrict__ W2,
                             unsigned short* __restrict__ W1T, unsigned short* __restrict__ W2T) {
    int i = blockIdx.x * 256 + threadIdx.x;
    if (i < CH1 * KCAT) {
        int n = i / KCAT, k = i - n * KCAT;
        float v = (k < 256) ? root1[(size_t)k * CH1 + n] : W1[(size_t)(k - 256) * CH1 + n];
        W1T[(size_t)n * KCAT + k] = f2bf(v);
    } else if (i < (CH1 + CH2) * KCAT) {
        int j = i - CH1 * KCAT;
        int n = j / KCAT, k = j - n * KCAT;
        float v = (k < 256) ? root2[(size_t)k * CH2 + n] : W2[(size_t)(k - 256) * CH2 + n];
        W2T[(size_t)n * KCAT + k] = f2bf(v);
    }
}

// ================= gather: one wave handles TWO (node, rel) segments =================
// Up to 8 independent row-loads in flight per wave (batch-issue, then accumulate).
__global__ __launch_bounds__(256) void gather_all(const unsigned short* __restrict__ xb,
                                                  const int* __restrict__ ss,
                                                  const int* __restrict__ off,
                                                  const int* __restrict__ cnt,
                                                  unsigned short* __restrict__ A,
                                                  int n0, int rows) {
    int wid  = blockIdx.x * 4 + (threadIdx.x >> 6);
    int lane = threadIdx.x & 63;
    if (wid >= rows * 4) return;
    int n  = wid >> 2;
    int r0 = (wid & 3) * 2;              // relations r0, r0+1
    int idx0  = r0 * NN + (n0 + n);
    int idx1  = idx0 + NN;
    int base0 = off[idx0], c0 = cnt[idx0];
    int base1 = off[idx1], c1 = cnt[idx1];

    f32x4 z = {0.f, 0.f, 0.f, 0.f};
    f32x4 a0 = z, a1 = z, a2 = z, a3 = z;
    f32x4 b0 = z, b1 = z, b2 = z, b3 = z;
    int j0 = 0, j1 = 0;
    while (j0 < c0 || j1 < c1) {        // all segment counts are wave-uniform
        int m0 = c0 - j0; m0 = (m0 > 4) ? 4 : m0;
        int m1 = c1 - j1; m1 = (m1 > 4) ? 4 : m1;
        ushort4 v00, v01, v02, v03, v10, v11, v12, v13;
        if (m0 > 0) v00 = ldrow(xb, ss[base0 + j0 + 0], lane);
        if (m0 > 1) v01 = ldrow(xb, ss[base0 + j0 + 1], lane);
        if (m0 > 2) v02 = ldrow(xb, ss[base0 + j0 + 2], lane);
        if (m0 > 3) v03 = ldrow(xb, ss[base0 + j0 + 3], lane);
        if (m1 > 0) v10 = ldrow(xb, ss[base1 + j1 + 0], lane);
        if (m1 > 1) v11 = ldrow(xb, ss[base1 + j1 + 1], lane);
        if (m1 > 2) v12 = ldrow(xb, ss[base1 + j1 + 2], lane);
        if (m1 > 3) v13 = ldrow(xb, ss[base1 + j1 + 3], lane);
        if (m0 > 0) a0 += cvt4(v00);
        if (m0 > 1) a1 += cvt4(v01);
        if (m0 > 2) a2 += cvt4(v02);
        if (m0 > 3) a3 += cvt4(v03);
        if (m1 > 0) b0 += cvt4(v10);
        if (m1 > 1) b1 += cvt4(v11);
        if (m1 > 2) b2 += cvt4(v12);
        if (m1 > 3) b3 += cvt4(v13);
        j0 += m0; j1 += m1;
    }
    f32x4 s0 = (a0 + a1) + (a2 + a3);
    f32x4 s1 = (b0 + b1) + (b2 + b3);
    float inv0 = (c0 > 0) ? 1.f / (float)c0 : 0.f;
    float inv1 = (c1 > 0) ? 1.f / (float)c1 : 0.f;
    ushort4 o0, o1;
    o0.x = f2bf(s0.x * inv0); o0.y = f2bf(s0.y * inv0);
    o0.z = f2bf(s0.z * inv0); o0.w = f2bf(s0.w * inv0);
    o1.x = f2bf(s1.x * inv1); o1.y = f2bf(s1.y * inv1);
    o1.z = f2bf(s1.z * inv1); o1.w = f2bf(s1.w * inv1);
    unsigned short* arow = A + (size_t)n * KA + r0 * 256;
    reinterpret_cast<ushort4*>(arow)[lane] = o0;
    reinterpret_cast<ushort4*>(arow + 256)[lane] = o1;
}

// ================= MFMA GEMM =================
// C[M x NOUT] = [Xsrc | A] @ BT^T + bias.  k<256 staged from Xsrc (L2-hot),
// k>=256 from A[M][KA].  global_load_lds width=16, linear LDS (m97 structure).
template<int NOUT, int BN, bool RELU_BF16>
__global__ __launch_bounds__(256) void gemm_mfma(const unsigned short* __restrict__ A,
                                                 const unsigned short* __restrict__ Xsrc,
                                                 const unsigned short* __restrict__ BT,
                                                 const float* __restrict__ bias,
                                                 void* __restrict__ Cout,
                                                 int M, int mrow0) {
    constexpr int MI = (BN == 128) ? 4 : 2;
    __shared__ __align__(16) unsigned short As[128 * 32];
    __shared__ __align__(16) unsigned short Bs[BN * 32];
    const int tid  = threadIdx.x;
    const int lane = tid & 63;
    const int w    = tid >> 6;
    const int wr   = (BN == 128) ? (w >> 1) : w;
    const int wc   = (BN == 128) ? (w & 1) : 0;
    const int wrow = wr * (MI * 16);
    const int wcol = wc * 64;
    const int row0 = blockIdx.x * 128;
    const int col0 = blockIdx.y * BN;

    const int srow = lane >> 2;
    const int skk  = (lane & 3) * 8;
    int ra0 = row0 + w * 16 + srow;
    int ra1 = row0 + 64 + w * 16 + srow;
    ra0 = (ra0 < M) ? ra0 : (M - 1);
    ra1 = (ra1 < M) ? ra1 : (M - 1);
    const unsigned short* pax0 = Xsrc + (size_t)(mrow0 + ra0) * 256 + skk;
    const unsigned short* pax1 = Xsrc + (size_t)(mrow0 + ra1) * 256 + skk;
    const unsigned short* paa0 = A + (size_t)ra0 * KA + skk - 256;   // +k0 valid for k0>=256
    const unsigned short* paa1 = A + (size_t)ra1 * KA + skk - 256;
    const unsigned short* pb0 = BT + (size_t)(col0 + w * 16 + srow) * KCAT + skk;
    const unsigned short* pb1 = BT + (size_t)(col0 + 64 + w * 16 + srow) * KCAT + skk;
    unsigned short* lA0 = As + w * 512;
    unsigned short* lA1 = As + 2048 + w * 512;
    unsigned short* lB0 = Bs + w * 512;
    unsigned short* lB1 = Bs + 2048 + w * 512;

    f32x4 acc[MI][4] = {};
    const int fr = lane & 15;
    const int ka = (lane >> 4) * 8;

    for (int k0 = 0; k0 < KCAT; k0 += 32) {
        const unsigned short* p0 = (k0 < 256) ? (pax0 + k0) : (paa0 + k0);
        const unsigned short* p1 = (k0 < 256) ? (pax1 + k0) : (paa1 + k0);
        __builtin_amdgcn_global_load_lds((const AS_GLOBAL unsigned int*)p0,
                                         (AS_LDS unsigned int*)lA0, 16, 0, 0);
        __builtin_amdgcn_global_load_lds((const AS_GLOBAL unsigned int*)p1,
                                         (AS_LDS unsigned int*)lA1, 16, 0, 0);
        __builtin_amdgcn_global_load_lds((const AS_GLOBAL unsigned int*)(pb0 + k0),
                                         (AS_LDS unsigned int*)lB0, 16, 0, 0);
        if (BN == 128)
            __builtin_amdgcn_global_load_lds((const AS_GLOBAL unsigned int*)(pb1 + k0),
                                             (AS_LDS unsigned int*)lB1, 16, 0, 0);
        __syncthreads();

        short8 af[MI], bfrag[4];
        #pragma unroll
        for (int i = 0; i < MI; ++i)
            af[i] = *reinterpret_cast<const short8*>(&As[(wrow + i * 16 + fr) * 32 + ka]);
        #pragma unroll
        for (int i = 0; i < 4; ++i)
            bfrag[i] = *reinterpret_cast<const short8*>(&Bs[(wcol + i * 16 + fr) * 32 + ka]);
        #pragma unroll
        for (int mi = 0; mi < MI; ++mi)
            #pragma unroll
            for (int ni = 0; ni < 4; ++ni)
                acc[mi][ni] = __builtin_amdgcn_mfma_f32_16x16x32_bf16(af[mi], bfrag[ni], acc[mi][ni], 0, 0, 0);
        __syncthreads();
    }

    #pragma unroll
    for (int mi = 0; mi < MI; ++mi) {
        #pragma unroll
        for (int q = 0; q < 4; ++q) {
            int gm = row0 + wrow + mi * 16 + (lane >> 4) * 4 + q;
            if (gm >= M) continue;
            #pragma unroll
            for (int ni = 0; ni < 4; ++ni) {
                int gn = col0 + wcol + ni * 16 + fr;
                float v = acc[mi][ni][q] + bias[gn];
                if (RELU_BF16) {
                    v = fmaxf(v, 0.f);
                    ((unsigned short*)Cout)[(size_t)(mrow0 + gm) * NOUT + gn] = f2bf(v);
                } else {
                    ((float*)Cout)[(size_t)(mrow0 + gm) * NOUT + gn] = v;
                }
            }
        }
    }
}

// ================= launch =================
extern "C" void kernel_launch(void* const* d_in, const int* in_sizes, int n_in,
                              void* d_out, int out_size, void* d_ws, size_t ws_size,
                              hipStream_t stream) {
    const float* x     = (const float*)d_in[0];
    const float* W1    = (const float*)d_in[1];
    const float* root1 = (const float*)d_in[2];
    const float* b1    = (const float*)d_in[3];
    const float* W2    = (const float*)d_in[4];
    const float* root2 = (const float*)d_in[5];
    const float* b2    = (const float*)d_in[6];
    const int*   ei    = (const int*)d_in[7];
    const int*   et    = (const int*)d_in[8];
    const int* src = ei;
    const int* dst = ei + NE;
    float* out = (float*)d_out;

    char* ws = (char*)d_ws;
    int*            cnt    = (int*)(ws + 0);           // 640000
    int*            off    = (int*)(ws + 640000);      // 640000
    int*            cursor = (int*)(ws + 1280000);     // 640000
    int*            bsum   = (int*)(ws + 1920000);     // pad to 3072
    int*            ss     = (int*)(ws + 1923072);     // 2560000
    unsigned short* x_bf   = (unsigned short*)(ws + 4483072);   // 10,240,000
    unsigned short* h_bf   = (unsigned short*)(ws + 14723072);  // 10,240,000
    unsigned short* W1T    = (unsigned short*)(ws + 24963072);  // 1,179,648
    unsigned short* W2T    = (unsigned short*)(ws + 26142720);  // 589,824
    unsigned short* A      = (unsigned short*)(ws + 26732544);  // up to 81,920,000

    // chunk rows by available workspace for A ([rows][KA] bf16)
    size_t availA = (ws_size > 26732544) ? ws_size - 26732544 : 0;
    int rowsC = (int)(availA / ((size_t)KA * 2));
    if (rowsC > NN) rowsC = NN;
    if (rowsC >= 256) rowsC &= ~127;
    if (rowsC < 1) rowsC = 1;

    const int NB = (NSEG + 255) / 256;   // 625

    // CSR + conversions
    hipMemsetAsync(cnt, 0, (size_t)NSEG * 4, stream);
    prologue1<<<(NN * 64 + 255) / 256, 256, 0, stream>>>(dst, et, cnt, x, x_bf);
    scan1<<<NB, 256, 0, stream>>>(cnt, off, bsum);
    scan2<<<1, 1024, 0, stream>>>(bsum, NB);
    scan3<<<NB, 256, 0, stream>>>(off, bsum, cursor);
    bucket_kernel<<<(NE + 255) / 256, 256, 0, stream>>>(src, dst, et, cursor, ss);
    build_wt_all<<<((CH1 + CH2) * KCAT + 255) / 256, 256, 0, stream>>>(root1, W1, root2, W2, W1T, W2T);

    // layer 1: h_bf = relu([x_bf | Agg(x)] @ W1T^T + b1)   [bf16 out]
    for (int n0 = 0; n0 < NN; n0 += rowsC) {
        int rows = (NN - n0 < rowsC) ? (NN - n0) : rowsC;
        gather_all<<<rows, 256, 0, stream>>>(x_bf, ss, off, cnt, A, n0, rows);
        dim3 g((rows + 127) / 128, CH1 / 128);
        gemm_mfma<CH1, 128, true><<<g, 256, 0, stream>>>(A, x_bf, W1T, b1, h_bf, rows, n0);
    }
    // layer 2: out = [h_bf | Agg(h)] @ W2T^T + b2   [fp32 out]
    for (int n0 = 0; n0 < NN; n0 += rowsC) {
        int rows = (NN - n0 < rowsC) ? (NN - n0) : rowsC;
        gather_all<<<rows, 256, 0, stream>>>(h_bf, ss, off, cnt, A, n0, rows);
        dim3 g((rows + 127) / 128, CH2 / 64);
        gemm_mfma<CH2, 64, false><<<g, 256, 0, stream>>>(A, h_bf, W2T, b2, out, rows, n0);
    }
}

// Round 10
// 408.437 us; speedup vs baseline: 1.1995x; 1.1995x over previous
//
#include <hip/hip_runtime.h>

#define NN 20000
#define NE 640000
#define NR 8
#define NSEG (NN * NR)
#define KCAT 2304            // logical K: 256 self + 8*256 relations
#define KA   2048            // A stores only the 8 relation blocks
#define CH1 256
#define CH2 128

typedef __attribute__((ext_vector_type(8))) short short8;
typedef __attribute__((ext_vector_type(4))) float f32x4;

#define AS_GLOBAL __attribute__((address_space(1)))
#define AS_LDS    __attribute__((address_space(3)))

__device__ __forceinline__ float bf2f(unsigned short u) {
    unsigned int x = ((unsigned int)u) << 16;
    return __builtin_bit_cast(float, x);
}
__device__ __forceinline__ unsigned short f2bf(float f) {
    unsigned int u = __builtin_bit_cast(unsigned int, f);
    u = (u + 0x7FFFu + ((u >> 16) & 1u)) >> 16;   // RNE
    return (unsigned short)u;
}
__device__ __forceinline__ f32x4 cvt4(ushort4 v) {
    f32x4 r;
    r.x = bf2f(v.x); r.y = bf2f(v.y); r.z = bf2f(v.z); r.w = bf2f(v.w);
    return r;
}

// ================= fused prologue: edge count + x->bf16 =================
__global__ void prologue1(const int* __restrict__ dst, const int* __restrict__ et,
                          int* __restrict__ cnt,
                          const float* __restrict__ x, unsigned short* __restrict__ xbf) {
    int gid = blockIdx.x * 256 + threadIdx.x;
    if (gid < NN * 64) {
        float4 v = reinterpret_cast<const float4*>(x)[gid];
        ushort4 o;
        o.x = f2bf(v.x); o.y = f2bf(v.y); o.z = f2bf(v.z); o.w = f2bf(v.w);
        reinterpret_cast<ushort4*>(xbf)[gid] = o;
    }
    if (gid < NE) atomicAdd(&cnt[et[gid] * NN + dst[gid]], 1);
}

// ================= scans =================
__global__ void scan1(const int* __restrict__ cnt, int* __restrict__ off,
                      int* __restrict__ bsum) {
    __shared__ int s[256];
    int i = blockIdx.x * 256 + threadIdx.x;
    int v = (i < NSEG) ? cnt[i] : 0;
    s[threadIdx.x] = v;
    __syncthreads();
    for (int d = 1; d < 256; d <<= 1) {
        int t = (threadIdx.x >= d) ? s[threadIdx.x - d] : 0;
        __syncthreads();
        s[threadIdx.x] += t;
        __syncthreads();
    }
    if (i < NSEG) off[i] = s[threadIdx.x] - v;
    if (threadIdx.x == 255) bsum[blockIdx.x] = s[255];
}

__global__ __launch_bounds__(1024) void scan2(int* __restrict__ bsum, int nb) {
    __shared__ int s[1024];
    int t = threadIdx.x;
    int v = (t < nb) ? bsum[t] : 0;
    s[t] = v;
    __syncthreads();
    for (int d = 1; d < 1024; d <<= 1) {
        int tv = (t >= d) ? s[t - d] : 0;
        __syncthreads();
        s[t] += tv;
        __syncthreads();
    }
    if (t < nb) bsum[t] = s[t] - v;   // exclusive
}

__global__ void scan3(int* __restrict__ off, const int* __restrict__ bsum,
                      int* __restrict__ cursor) {
    int i = blockIdx.x * 256 + threadIdx.x;
    if (i < NSEG) {
        int o = off[i] + bsum[blockIdx.x];
        off[i] = o;
        cursor[i] = o;
    }
}

__global__ void bucket_kernel(const int* __restrict__ src, const int* __restrict__ dst,
                              const int* __restrict__ et, int* __restrict__ cursor,
                              int* __restrict__ ss) {
    int e = blockIdx.x * blockDim.x + threadIdx.x;
    if (e < NE) {
        int p = atomicAdd(&cursor[et[e] * NN + dst[e]], 1);
        ss[p] = src[e];
    }
}

// ================= both weight transposes in one kernel =================
__global__ void build_wt_all(const float* __restrict__ root1, const float* __restrict__ W1,
                             const float* __restrict__ root2, const float* __restrict__ W2,
                             unsigned short* __restrict__ W1T, unsigned short* __restrict__ W2T) {
    int i = blockIdx.x * 256 + threadIdx.x;
    if (i < CH1 * KCAT) {
        int n = i / KCAT, k = i - n * KCAT;
        float v = (k < 256) ? root1[(size_t)k * CH1 + n] : W1[(size_t)(k - 256) * CH1 + n];
        W1T[(size_t)n * KCAT + k] = f2bf(v);
    } else if (i < (CH1 + CH2) * KCAT) {
        int j = i - CH1 * KCAT;
        int n = j / KCAT, k = j - n * KCAT;
        float v = (k < 256) ? root2[(size_t)k * CH2 + n] : W2[(size_t)(k - 256) * CH2 + n];
        W2T[(size_t)n * KCAT + k] = f2bf(v);
    }
}

// ================= gather: one wave per (node, rel) segment =================
// Unroll-4 with independent accumulators: 4 row-gathers in flight per wave.
__global__ __launch_bounds__(256) void gather_all(const unsigned short* __restrict__ xb,
                                                  const int* __restrict__ ss,
                                                  const int* __restrict__ off,
                                                  const int* __restrict__ cnt,
                                                  unsigned short* __restrict__ A,
                                                  int n0, int rows) {
    int wid  = blockIdx.x * 4 + (threadIdx.x >> 6);
    int lane = threadIdx.x & 63;
    if (wid >= rows * NR) return;
    int n = wid >> 3;          // NR == 8
    int r = wid & 7;
    int idx  = r * NN + (n0 + n);
    int base = off[idx];
    int c    = cnt[idx];

    f32x4 z = {0.f, 0.f, 0.f, 0.f};
    f32x4 a0 = z, a1 = z, a2 = z, a3 = z;
    int jj = 0;
    for (; jj + 4 <= c; jj += 4) {
        int s0 = ss[base + jj + 0];
        int s1 = ss[base + jj + 1];
        int s2 = ss[base + jj + 2];
        int s3 = ss[base + jj + 3];
        ushort4 v0 = reinterpret_cast<const ushort4*>(xb + (size_t)s0 * 256)[lane];
        ushort4 v1 = reinterpret_cast<const ushort4*>(xb + (size_t)s1 * 256)[lane];
        ushort4 v2 = reinterpret_cast<const ushort4*>(xb + (size_t)s2 * 256)[lane];
        ushort4 v3 = reinterpret_cast<const ushort4*>(xb + (size_t)s3 * 256)[lane];
        a0 += cvt4(v0); a1 += cvt4(v1); a2 += cvt4(v2); a3 += cvt4(v3);
    }
    int rem = c - jj;   // 0..3, wave-uniform
    if (rem > 0) {
        int s0 = ss[base + jj + 0];
        int s1 = (rem > 1) ? ss[base + jj + 1] : s0;
        int s2 = (rem > 2) ? ss[base + jj + 2] : s0;
        ushort4 v0 = reinterpret_cast<const ushort4*>(xb + (size_t)s0 * 256)[lane];
        ushort4 v1 = (rem > 1) ? reinterpret_cast<const ushort4*>(xb + (size_t)s1 * 256)[lane] : make_ushort4(0,0,0,0);
        ushort4 v2 = (rem > 2) ? reinterpret_cast<const ushort4*>(xb + (size_t)s2 * 256)[lane] : make_ushort4(0,0,0,0);
        a0 += cvt4(v0);
        if (rem > 1) a1 += cvt4(v1);
        if (rem > 2) a2 += cvt4(v2);
    }
    f32x4 acc = (a0 + a1) + (a2 + a3);
    float inv = (c > 0) ? 1.f / (float)c : 0.f;
    ushort4 o;
    o.x = f2bf(acc.x * inv); o.y = f2bf(acc.y * inv);
    o.z = f2bf(acc.z * inv); o.w = f2bf(acc.w * inv);
    reinterpret_cast<ushort4*>(A + (size_t)n * KA + r * 256)[lane] = o;
}

// ================= MFMA GEMM =================
// C[M x NOUT] = [Xsrc | A] @ BT^T + bias.  k<256 staged from Xsrc (L2-hot),
// k>=256 from A[M][KA].  BM=64 doubles block count vs 128 (CU overlap).
// Wave grid 2x2; wave tile (BM/2) x (BN/2).
template<int NOUT, int BM, int BN, bool RELU_BF16>
__global__ __launch_bounds__(256) void gemm_mfma(const unsigned short* __restrict__ A,
                                                 const unsigned short* __restrict__ Xsrc,
                                                 const unsigned short* __restrict__ BT,
                                                 const float* __restrict__ bias,
                                                 void* __restrict__ Cout,
                                                 int M, int mrow0) {
    constexpr int MI = BM / 32;     // 16-row frags per wave (BM/2/16)
    constexpr int NI = BN / 32;
    __shared__ __align__(16) unsigned short As[BM * 32];
    __shared__ __align__(16) unsigned short Bs[BN * 32];
    const int tid  = threadIdx.x;
    const int lane = tid & 63;
    const int w    = tid >> 6;
    const int wr   = w >> 1, wc = w & 1;
    const int wrow = wr * (MI * 16);
    const int wcol = wc * (NI * 16);
    const int row0 = blockIdx.x * BM;
    const int col0 = blockIdx.y * BN;

    const int srow = lane >> 2;
    const int skk  = (lane & 3) * 8;
    int ra0 = row0 + w * 16 + srow;
    int ra1 = row0 + 64 + w * 16 + srow;       // BM==128 only
    ra0 = (ra0 < M) ? ra0 : (M - 1);
    ra1 = (ra1 < M) ? ra1 : (M - 1);
    const unsigned short* pax0 = Xsrc + (size_t)(mrow0 + ra0) * 256 + skk;
    const unsigned short* pax1 = Xsrc + (size_t)(mrow0 + ra1) * 256 + skk;
    const unsigned short* paa0 = A + (size_t)ra0 * KA + skk - 256;   // +k0 valid for k0>=256
    const unsigned short* paa1 = A + (size_t)ra1 * KA + skk - 256;
    const unsigned short* pb0 = BT + (size_t)(col0 + w * 16 + srow) * KCAT + skk;
    const unsigned short* pb1 = BT + (size_t)(col0 + 64 + w * 16 + srow) * KCAT + skk; // BN==128 only
    unsigned short* lA0 = As + w * 512;
    unsigned short* lA1 = As + 2048 + w * 512;
    unsigned short* lB0 = Bs + w * 512;
    unsigned short* lB1 = Bs + 2048 + w * 512;

    f32x4 acc[MI][NI] = {};
    const int fr = lane & 15;
    const int ka = (lane >> 4) * 8;

    for (int k0 = 0; k0 < KCAT; k0 += 32) {
        const unsigned short* p0 = (k0 < 256) ? (pax0 + k0) : (paa0 + k0);
        __builtin_amdgcn_global_load_lds((const AS_GLOBAL unsigned int*)p0,
                                         (AS_LDS unsigned int*)lA0, 16, 0, 0);
        if (BM == 128) {
            const unsigned short* p1 = (k0 < 256) ? (pax1 + k0) : (paa1 + k0);
            __builtin_amdgcn_global_load_lds((const AS_GLOBAL unsigned int*)p1,
                                             (AS_LDS unsigned int*)lA1, 16, 0, 0);
        }
        __builtin_amdgcn_global_load_lds((const AS_GLOBAL unsigned int*)(pb0 + k0),
                                         (AS_LDS unsigned int*)lB0, 16, 0, 0);
        if (BN == 128)
            __builtin_amdgcn_global_load_lds((const AS_GLOBAL unsigned int*)(pb1 + k0),
                                             (AS_LDS unsigned int*)lB1, 16, 0, 0);
        __syncthreads();

        short8 af[MI], bfrag[NI];
        #pragma unroll
        for (int i = 0; i < MI; ++i)
            af[i] = *reinterpret_cast<const short8*>(&As[(wrow + i * 16 + fr) * 32 + ka]);
        #pragma unroll
        for (int i = 0; i < NI; ++i)
            bfrag[i] = *reinterpret_cast<const short8*>(&Bs[(wcol + i * 16 + fr) * 32 + ka]);
        #pragma unroll
        for (int mi = 0; mi < MI; ++mi)
            #pragma unroll
            for (int ni = 0; ni < NI; ++ni)
                acc[mi][ni] = __builtin_amdgcn_mfma_f32_16x16x32_bf16(af[mi], bfrag[ni], acc[mi][ni], 0, 0, 0);
        __syncthreads();
    }

    #pragma unroll
    for (int mi = 0; mi < MI; ++mi) {
        #pragma unroll
        for (int q = 0; q < 4; ++q) {
            int gm = row0 + wrow + mi * 16 + (lane >> 4) * 4 + q;
            if (gm >= M) continue;
            #pragma unroll
            for (int ni = 0; ni < NI; ++ni) {
                int gn = col0 + wcol + ni * 16 + fr;
                float v = acc[mi][ni][q] + bias[gn];
                if (RELU_BF16) {
                    v = fmaxf(v, 0.f);
                    ((unsigned short*)Cout)[(size_t)(mrow0 + gm) * NOUT + gn] = f2bf(v);
                } else {
                    ((float*)Cout)[(size_t)(mrow0 + gm) * NOUT + gn] = v;
                }
            }
        }
    }
}

// ================= launch =================
extern "C" void kernel_launch(void* const* d_in, const int* in_sizes, int n_in,
                              void* d_out, int out_size, void* d_ws, size_t ws_size,
                              hipStream_t stream) {
    const float* x     = (const float*)d_in[0];
    const float* W1    = (const float*)d_in[1];
    const float* root1 = (const float*)d_in[2];
    const float* b1    = (const float*)d_in[3];
    const float* W2    = (const float*)d_in[4];
    const float* root2 = (const float*)d_in[5];
    const float* b2    = (const float*)d_in[6];
    const int*   ei    = (const int*)d_in[7];
    const int*   et    = (const int*)d_in[8];
    const int* src = ei;
    const int* dst = ei + NE;
    float* out = (float*)d_out;

    char* ws = (char*)d_ws;
    int*            cnt    = (int*)(ws + 0);           // 640000
    int*            off    = (int*)(ws + 640000);      // 640000
    int*            cursor = (int*)(ws + 1280000);     // 640000
    int*            bsum   = (int*)(ws + 1920000);     // pad to 3072
    int*            ss     = (int*)(ws + 1923072);     // 2560000
    unsigned short* x_bf   = (unsigned short*)(ws + 4483072);   // 10,240,000
    unsigned short* h_bf   = (unsigned short*)(ws + 14723072);  // 10,240,000
    unsigned short* W1T    = (unsigned short*)(ws + 24963072);  // 1,179,648
    unsigned short* W2T    = (unsigned short*)(ws + 26142720);  // 589,824
    unsigned short* A      = (unsigned short*)(ws + 26732544);  // up to 81,920,000

    // chunk rows by available workspace for A ([rows][KA] bf16)
    size_t availA = (ws_size > 26732544) ? ws_size - 26732544 : 0;
    int rowsC = (int)(availA / ((size_t)KA * 2));
    if (rowsC > NN) rowsC = NN;
    if (rowsC >= 256) rowsC &= ~127;
    if (rowsC < 1) rowsC = 1;

    const int NB = (NSEG + 255) / 256;   // 625

    // CSR + conversions
    hipMemsetAsync(cnt, 0, (size_t)NSEG * 4, stream);
    prologue1<<<(NN * 64 + 255) / 256, 256, 0, stream>>>(dst, et, cnt, x, x_bf);
    scan1<<<NB, 256, 0, stream>>>(cnt, off, bsum);
    scan2<<<1, 1024, 0, stream>>>(bsum, NB);
    scan3<<<NB, 256, 0, stream>>>(off, bsum, cursor);
    bucket_kernel<<<(NE + 255) / 256, 256, 0, stream>>>(src, dst, et, cursor, ss);
    build_wt_all<<<((CH1 + CH2) * KCAT + 255) / 256, 256, 0, stream>>>(root1, W1, root2, W2, W1T, W2T);

    // layer 1: h_bf = relu([x_bf | Agg(x)] @ W1T^T + b1)   [bf16 out]
    for (int n0 = 0; n0 < NN; n0 += rowsC) {
        int rows = (NN - n0 < rowsC) ? (NN - n0) : rowsC;
        gather_all<<<(rows * NR + 3) / 4, 256, 0, stream>>>(x_bf, ss, off, cnt, A, n0, rows);
        dim3 g((rows + 63) / 64, CH1 / 128);
        gemm_mfma<CH1, 64, 128, true><<<g, 256, 0, stream>>>(A, x_bf, W1T, b1, h_bf, rows, n0);
    }
    // layer 2: out = [h_bf | Agg(h)] @ W2T^T + b2   [fp32 out]
    for (int n0 = 0; n0 < NN; n0 += rowsC) {
        int rows = (NN - n0 < rowsC) ? (NN - n0) : rowsC;
        gather_all<<<(rows * NR + 3) / 4, 256, 0, stream>>>(h_bf, ss, off, cnt, A, n0, rows);
        dim3 g((rows + 63) / 64, CH2 / 64);
        gemm_mfma<CH2, 64, 64, false><<<g, 256, 0, stream>>>(A, h_bf, W2T, b2, out, rows, n0);
    }
}